// Round 11
// baseline (292.220 us; speedup 1.0000x reference)
//
#include <hip/hip_runtime.h>

#define N_NODES  100000
#define M_PAD    100096   // 782 * 128
#define N_EDGES  1600000
#define N_GRAPHS 512
#define IN_DIM   128
#define HID_DIM  256
#define OUT_DIM  128

#define NB       782      // buckets of 128 nodes
#define BCAP     3072     // mean 2048, +22 sigma headroom
#define CHUNK    16384    // edges per bucket block (v12: 2048->16384 to kill
                          // pairBuf 64B-line write amplification: 2.6 entries
                          // (10B)/bucket/block -> 21 entries (84B))
#define BKB      ((N_EDGES + CHUNK - 1) / CHUNK)   // 98
#define GC_STRIDE 16      // gcursor padded to one counter per 64B line

typedef __bf16 bf16x8 __attribute__((ext_vector_type(8)));
typedef __bf16 bf16x4 __attribute__((ext_vector_type(4)));
typedef __bf16 bf16x2 __attribute__((ext_vector_type(2)));
typedef float  f32x4  __attribute__((ext_vector_type(4)));

// ---- packed weight buffer layout (frag-ordered, LINEAR group stream) ----
#define WP_L2_BASE 32768
#define WP_L3_BASE 98304
#define WP_TOTAL   131072

// ---- fused init+bucket grid ----
#define R_X    (N_NODES * IN_DIM / 4)
#define R_APAD ((M_PAD - N_NODES) * IN_DIM / 4)
#define R_WP   WP_TOTAL
#define R_OUT  (N_GRAPHS * OUT_DIM / 4)
#define R_TOTAL (R_X + R_APAD + R_WP + R_OUT)
#define NI     ((R_TOTAL + 255) / 256)
#define GRID_IB (BKB + NI)

// ---------------- fused init + edge binning ----------------
__global__ __launch_bounds__(256) void init_bucket_kernel(const float* __restrict__ x,
                                                          const float* __restrict__ W1,
                                                          const float* __restrict__ W2,
                                                          const float* __restrict__ Wo,
                                                          const int* __restrict__ ei,
                                                          __bf16* __restrict__ xb,
                                                          __bf16* __restrict__ Apad,
                                                          __bf16* __restrict__ Wp,
                                                          float* __restrict__ outbuf,
                                                          int* __restrict__ gcursor,
                                                          unsigned* __restrict__ pairBuf) {
    __shared__ int lcnt[NB];
    __shared__ int lbase[NB];
    const int tid = threadIdx.x;

    if (blockIdx.x < BKB) {
        // ---- bucket path ----
        const int e0 = blockIdx.x * CHUNK;

        for (int b = tid; b < NB; b += 256) lcnt[b] = 0;
        __syncthreads();

        for (int i = tid; i < CHUNK; i += 256) {
            int e = e0 + i;
            if (e < N_EDGES) atomicAdd(&lcnt[ei[N_EDGES + e] >> 7], 1);
        }
        __syncthreads();

        for (int b = tid; b < NB; b += 256) {
            int c = lcnt[b];
            // padded counter: one per 64B line (kills cross-block line serialization)
            lbase[b] = c ? atomicAdd(&gcursor[b * GC_STRIDE], c) : 0;
            lcnt[b] = 0;
        }
        __syncthreads();

        for (int i = tid; i < CHUNK; i += 256) {
            int e = e0 + i;
            if (e < N_EDGES) {
                int s = ei[e];
                int d = ei[N_EDGES + e];
                int b = d >> 7;
                int pos = lbase[b] + atomicAdd(&lcnt[b], 1);
                if (pos < BCAP)
                    pairBuf[(size_t)b * BCAP + pos] = (unsigned)s | ((unsigned)(d & 127) << 17);
            }
        }
        return;
    }

    // ---- init path ----
    long long i = (long long)(blockIdx.x - BKB) * blockDim.x + tid;
    if (i < R_X) {
        float4 v = ((const float4*)x)[i];
        bf16x4 h;
        h.x = (__bf16)v.x; h.y = (__bf16)v.y; h.z = (__bf16)v.z; h.w = (__bf16)v.w;
        ((bf16x4*)xb)[i] = h;
        return;
    }
    i -= R_X;
    if (i < R_APAD) {
        bf16x4 z; z.x = (__bf16)0.f; z.y = (__bf16)0.f; z.z = (__bf16)0.f; z.w = (__bf16)0.f;
        ((bf16x4*)Apad)[i] = z;
        return;
    }
    i -= R_APAD;
    if (i < R_WP) {
        int idx = (int)i;
        const float* src;
        int K, Nn, base;
        if (idx < WP_L2_BASE)      { src = W1; K = 128; Nn = 256; base = 0; }
        else if (idx < WP_L3_BASE) { src = W2; K = 256; Nn = 256; base = WP_L2_BASE; }
        else                       { src = Wo; K = 256; Nn = 128; base = WP_L3_BASE; }
        int r0 = idx - base;
        int slabElems = 32 * K;          // power of two
        int j = r0 / slabElems;
        int r = r0 % slabElems;
        int KS = K / 32;
        int p = r >> 9;
        int lane = (r >> 3) & 63;
        int e = r & 7;
        int s = p % KS, t = p / KS;
        int quad = lane >> 4, l16 = lane & 15;
        int n = j * 32 + t * 16 + l16;
        int k = s * 32 + quad * 8 + e;
        Wp[idx] = (__bf16)src[(size_t)k * Nn + n];
        return;
    }
    i -= R_WP;
    if (i < R_OUT) {
        ((float4*)outbuf)[i] = make_float4(0.f, 0.f, 0.f, 0.f);
        return;
    }
}

// ---------------- aggB: fused per-bucket CSR build (LDS) + gather aggregate ----------------
#define AGG_THREADS 512

__global__ __launch_bounds__(AGG_THREADS) void aggB_kernel(const unsigned* __restrict__ pairBuf,
                                                           const int* __restrict__ gcursor,
                                                           const __bf16* __restrict__ xb,
                                                           __bf16* __restrict__ A) {
    __shared__ int lcnt[128];
    __shared__ int loffs[128];
    __shared__ int lcur[128];
    __shared__ int offx[128];
    __shared__ unsigned sorted[BCAP];   // 12 KB

    const int b = blockIdx.x;
    const int tid = threadIdx.x;
    const int node0 = b << 7;
    const int cnt = min(gcursor[b * GC_STRIDE], BCAP);
    const unsigned* pb = pairBuf + (size_t)b * BCAP;

    if (tid < 128) { lcnt[tid] = 0; lcur[tid] = 0; }
    __syncthreads();

    for (int i = tid; i < cnt; i += AGG_THREADS)
        atomicAdd(&lcnt[pb[i] >> 17], 1);
    __syncthreads();

    if (tid < 128) loffs[tid] = lcnt[tid];
    __syncthreads();
    for (int st = 1; st < 128; st <<= 1) {
        int add = (tid < 128 && tid >= st) ? loffs[tid - st] : 0;
        __syncthreads();
        if (tid < 128) loffs[tid] += add;
        __syncthreads();
    }
    if (tid < 128) offx[tid] = loffs[tid] - lcnt[tid];
    __syncthreads();

    for (int i = tid; i < cnt; i += AGG_THREADS) {
        unsigned u = pb[i];
        int dl = u >> 17;
        int slot = atomicAdd(&lcur[dl], 1);
        sorted[offx[dl] + slot] = u & 0x1FFFF;
    }
    __syncthreads();

    // ---- phase 2: 8 waves x 16 nodes, register-accumulated gather ----
    const int wid = tid >> 6;
    const int lane = tid & 63;
    const int c0 = lane * 2;

    #pragma unroll 1
    for (int n = wid; n < 128; n += (AGG_THREADS / 64)) {
        int v = node0 + n;
        if (v >= N_NODES) break;            // wave-uniform; later n only larger
        int off = offx[n];
        int len = lcnt[n];
        bf16x2 self = *(const bf16x2*)(xb + (size_t)v * IN_DIM + c0);
        float ax = (float)self.x, ay = (float)self.y;

        int addr = off + lane;
        if (addr >= cnt) addr = (cnt > 0) ? cnt - 1 : 0;
        int myidx = (int)sorted[addr];

        int lim = len < 64 ? len : 64;
        int j = 0;
        for (; j + 8 <= lim; j += 8) {
            int s0 = __shfl(myidx, j + 0, 64);
            int s1 = __shfl(myidx, j + 1, 64);
            int s2 = __shfl(myidx, j + 2, 64);
            int s3 = __shfl(myidx, j + 3, 64);
            int s4 = __shfl(myidx, j + 4, 64);
            int s5 = __shfl(myidx, j + 5, 64);
            int s6 = __shfl(myidx, j + 6, 64);
            int s7 = __shfl(myidx, j + 7, 64);
            bf16x2 v0 = *(const bf16x2*)(xb + (size_t)s0 * IN_DIM + c0);
            bf16x2 v1 = *(const bf16x2*)(xb + (size_t)s1 * IN_DIM + c0);
            bf16x2 v2 = *(const bf16x2*)(xb + (size_t)s2 * IN_DIM + c0);
            bf16x2 v3 = *(const bf16x2*)(xb + (size_t)s3 * IN_DIM + c0);
            bf16x2 v4 = *(const bf16x2*)(xb + (size_t)s4 * IN_DIM + c0);
            bf16x2 v5 = *(const bf16x2*)(xb + (size_t)s5 * IN_DIM + c0);
            bf16x2 v6 = *(const bf16x2*)(xb + (size_t)s6 * IN_DIM + c0);
            bf16x2 v7 = *(const bf16x2*)(xb + (size_t)s7 * IN_DIM + c0);
            ax += (float)v0.x + (float)v1.x + (float)v2.x + (float)v3.x
                + (float)v4.x + (float)v5.x + (float)v6.x + (float)v7.x;
            ay += (float)v0.y + (float)v1.y + (float)v2.y + (float)v3.y
                + (float)v4.y + (float)v5.y + (float)v6.y + (float)v7.y;
        }
        for (; j < lim; ++j) {
            int s = __shfl(myidx, j, 64);
            bf16x2 vv = *(const bf16x2*)(xb + (size_t)s * IN_DIM + c0);
            ax += (float)vv.x;
            ay += (float)vv.y;
        }
        for (; j < len; ++j) {
            int s = (int)sorted[off + j];
            bf16x2 vv = *(const bf16x2*)(xb + (size_t)s * IN_DIM + c0);
            ax += (float)vv.x;
            ay += (float)vv.y;
        }
        bf16x2 h;
        h.x = (__bf16)ax;
        h.y = (__bf16)ay;
        *(bf16x2*)(A + (size_t)v * IN_DIM + c0) = h;
    }
}

// ---------------- fused 3-layer MLP + pool (v2 core FROZEN; epilogue v11) ----------------
__device__ __forceinline__ void load_group_p(const __bf16* __restrict__ p, int lane,
                                             bf16x8* __restrict__ dst) {
    #pragma unroll
    for (int e = 0; e < 8; ++e)
        dst[e] = *(const bf16x8*)(p + (e * 64 + lane) * 8);
}

__device__ __forceinline__ void store_H(__bf16* __restrict__ H, int j, int quad, int l16,
                                        const f32x4 (&acc)[2][2], float bt0, float bt1) {
    const int c7 = l16 & 7;
    const int ch = l16 >> 3;
    #pragma unroll
    for (int i = 0; i < 2; ++i)
        #pragma unroll
        for (int t = 0; t < 2; ++t) {
            const float bb = t ? bt1 : bt0;
            #pragma unroll
            for (int rr = 0; rr < 4; ++rr) {
                int row = i * 16 + quad * 4 + rr;
                int cidx = (j * 4 + t * 2 + ch + row) & 31;
                float v = fmaxf(acc[i][t][rr] + bb, 0.f);
                H[row * 256 + cidx * 8 + c7] = (__bf16)v;
            }
        }
}

__global__ __launch_bounds__(64) void mlp_fused(const __bf16* __restrict__ A,
                                                const __bf16* __restrict__ Wp,
                                                const float* __restrict__ b1,
                                                const float* __restrict__ b2,
                                                const float* __restrict__ bo,
                                                float* __restrict__ out,
                                                const int* __restrict__ batch) {
    __shared__ __bf16 H[32 * 256];   // 16 KB

    const int lane = threadIdx.x;
    const int quad = lane >> 4, l16 = lane & 15;
    const size_t mblk = (size_t)blockIdx.x * 32;
    const int r0g = (int)mblk;

    bf16x8 a[2][8];
    bf16x8 buf0[8];
    bf16x8 buf1[8];

    const __bf16* wp = Wp;
    load_group_p(wp, lane, buf0);    // group 0

    // layer-1 A-frags
    #pragma unroll
    for (int i = 0; i < 2; ++i)
        #pragma unroll
        for (int s = 0; s < 4; ++s)
            a[i][s] = *(const bf16x8*)(A + (mblk + i * 16 + l16) * IN_DIM + s * 32 + quad * 8);

    // ---- layer 1: groups 0..7 ----
    #pragma unroll 1
    for (int j = 0; j < 8; j += 2) {
        {
            load_group_p(wp + 4096, lane, buf1);
            float bt0 = b1[j * 32 + l16];
            float bt1 = b1[j * 32 + 16 + l16];
            f32x4 acc[2][2] = {};
            #pragma unroll
            for (int p = 0; p < 8; ++p) {
                const int t = p >> 2, s = p & 3;
                acc[0][t] = __builtin_amdgcn_mfma_f32_16x16x32_bf16(a[0][s], buf0[p], acc[0][t], 0, 0, 0);
                acc[1][t] = __builtin_amdgcn_mfma_f32_16x16x32_bf16(a[1][s], buf0[p], acc[1][t], 0, 0, 0);
            }
            store_H(H, j, quad, l16, acc, bt0, bt1);
        }
        {
            load_group_p(wp + 8192, lane, buf0);
            float bt0 = b1[(j + 1) * 32 + l16];
            float bt1 = b1[(j + 1) * 32 + 16 + l16];
            f32x4 acc[2][2] = {};
            #pragma unroll
            for (int p = 0; p < 8; ++p) {
                const int t = p >> 2, s = p & 3;
                acc[0][t] = __builtin_amdgcn_mfma_f32_16x16x32_bf16(a[0][s], buf1[p], acc[0][t], 0, 0, 0);
                acc[1][t] = __builtin_amdgcn_mfma_f32_16x16x32_bf16(a[1][s], buf1[p], acc[1][t], 0, 0, 0);
            }
            store_H(H, j + 1, quad, l16, acc, bt0, bt1);
        }
        wp += 8192;
    }
    __syncthreads();

    // ---- layer 2 A-frags from LDS ----
    #pragma unroll
    for (int i = 0; i < 2; ++i)
        #pragma unroll
        for (int s = 0; s < 8; ++s) {
            int row = i * 16 + l16;
            a[i][s] = *(const bf16x8*)(H + row * 256 + (((s * 4 + quad) + row) & 31) * 8);
        }
    __syncthreads();

    // ---- layer 2: groups 8..23 ----
    #pragma unroll 1
    for (int j = 0; j < 8; ++j) {
        load_group_p(wp + 4096, lane, buf1);
        float bt0 = b2[j * 32 + l16];
        float bt1 = b2[j * 32 + 16 + l16];
        f32x4 acc[2][2] = {};
        #pragma unroll
        for (int p = 0; p < 8; ++p) {
            acc[0][0] = __builtin_amdgcn_mfma_f32_16x16x32_bf16(a[0][p], buf0[p], acc[0][0], 0, 0, 0);
            acc[1][0] = __builtin_amdgcn_mfma_f32_16x16x32_bf16(a[1][p], buf0[p], acc[1][0], 0, 0, 0);
        }
        load_group_p(wp + 8192, lane, buf0);
        #pragma unroll
        for (int p = 0; p < 8; ++p) {
            acc[0][1] = __builtin_amdgcn_mfma_f32_16x16x32_bf16(a[0][p], buf1[p], acc[0][1], 0, 0, 0);
            acc[1][1] = __builtin_amdgcn_mfma_f32_16x16x32_bf16(a[1][p], buf1[p], acc[1][1], 0, 0, 0);
        }
        store_H(H, j, quad, l16, acc, bt0, bt1);
        wp += 8192;
    }
    __syncthreads();

    // ---- layer 3 A-frags from LDS ----
    #pragma unroll
    for (int i = 0; i < 2; ++i)
        #pragma unroll
        for (int s = 0; s < 8; ++s) {
            int row = i * 16 + l16;
            a[i][s] = *(const bf16x8*)(H + row * 256 + (((s * 4 + quad) + row) & 31) * 8);
        }

    // ---- epilogue metadata (once): tile graph range + per-row graph ids ----
    const bool fulltile = (r0g + 31 < N_NODES);
    int gfirst = (r0g < N_NODES) ? batch[r0g] : -1;
    int glastE = -2;
    if (r0g < N_NODES) {
        int mlast = r0g + 31;
        if (mlast >= N_NODES) mlast = N_NODES - 1;
        glastE = batch[mlast];
    }
    int gm[2][4];
    #pragma unroll
    for (int i = 0; i < 2; ++i)
        #pragma unroll
        for (int rr = 0; rr < 4; ++rr) {
            int m = r0g + i * 16 + quad * 4 + rr;
            gm[i][rr] = (m < N_NODES) ? batch[m] : -1;
        }
    const bool fast = fulltile && (gfirst == glastE);

    // ---- layer 3: groups 24..31 (4 slabs), pooled atomic output ----
    #pragma unroll 1
    for (int j = 0; j < 4; ++j) {
        load_group_p(wp + 4096, lane, buf1);
        float bt0 = bo[j * 32 + l16];
        float bt1 = bo[j * 32 + 16 + l16];
        f32x4 acc[2][2] = {};
        #pragma unroll
        for (int p = 0; p < 8; ++p) {
            acc[0][0] = __builtin_amdgcn_mfma_f32_16x16x32_bf16(a[0][p], buf0[p], acc[0][0], 0, 0, 0);
            acc[1][0] = __builtin_amdgcn_mfma_f32_16x16x32_bf16(a[1][p], buf0[p], acc[1][0], 0, 0, 0);
        }
        load_group_p(wp + 8192, lane, buf0);  // last iter reads past Wp into pairBuf (harmless)
        #pragma unroll
        for (int p = 0; p < 8; ++p) {
            acc[0][1] = __builtin_amdgcn_mfma_f32_16x16x32_bf16(a[0][p], buf1[p], acc[0][1], 0, 0, 0);
            acc[1][1] = __builtin_amdgcn_mfma_f32_16x16x32_bf16(a[1][p], buf1[p], acc[1][1], 0, 0, 0);
        }

        if (fast) {
            #pragma unroll
            for (int t = 0; t < 2; ++t) {
                float sum = 0.f;
                #pragma unroll
                for (int i = 0; i < 2; ++i)
                    #pragma unroll
                    for (int rr = 0; rr < 4; ++rr) sum += acc[i][t][rr];
                sum += __shfl_xor(sum, 16, 64);
                sum += __shfl_xor(sum, 32, 64);
                if (quad == 0) {
                    int c = j * 32 + t * 16 + l16;
                    float bb = t ? bt1 : bt0;
                    atomicAdd(out + (size_t)gfirst * OUT_DIM + c, sum + 32.f * bb);
                }
            }
        } else {
            // per-graph masked reduction: one atomic per col per graph
            #pragma unroll 1
            for (int dg = gfirst; dg <= glastE; ++dg) {
                float cntv = 0.f;
                #pragma unroll
                for (int i = 0; i < 2; ++i)
                    #pragma unroll
                    for (int rr = 0; rr < 4; ++rr)
                        if (gm[i][rr] == dg) cntv += 1.f;
                cntv += __shfl_xor(cntv, 16, 64);
                cntv += __shfl_xor(cntv, 32, 64);
                #pragma unroll
                for (int t = 0; t < 2; ++t) {
                    float s = 0.f;
                    #pragma unroll
                    for (int i = 0; i < 2; ++i)
                        #pragma unroll
                        for (int rr = 0; rr < 4; ++rr)
                            if (gm[i][rr] == dg) s += acc[i][t][rr];
                    s += __shfl_xor(s, 16, 64);
                    s += __shfl_xor(s, 32, 64);
                    if (quad == 0) {
                        int c = j * 32 + t * 16 + l16;
                        float bb = t ? bt1 : bt0;
                        atomicAdd(out + (size_t)dg * OUT_DIM + c, s + cntv * bb);
                    }
                }
            }
        }
        wp += 8192;
    }
}

extern "C" void kernel_launch(void* const* d_in, const int* in_sizes, int n_in,
                              void* d_out, int out_size, void* d_ws, size_t ws_size,
                              hipStream_t stream) {
    const float* x  = (const float*)d_in[0];
    const int*   ei = (const int*)d_in[1];
    const int*   bi = (const int*)d_in[2];
    const float* W1 = (const float*)d_in[3];
    const float* b1 = (const float*)d_in[4];
    const float* W2 = (const float*)d_in[5];
    const float* b2 = (const float*)d_in[6];
    const float* Wo = (const float*)d_in[7];
    const float* bo = (const float*)d_in[8];
    float* out = (float*)d_out;

    __bf16* A  = (__bf16*)d_ws;                        // [M_PAD][128]
    __bf16* xb = A + (size_t)M_PAD * IN_DIM;           // [N_NODES][128]
    __bf16* Wp = xb + (size_t)N_NODES * IN_DIM;        // [131072] packed frag-ordered
    unsigned* pairBuf = (unsigned*)(Wp + WP_TOTAL);    // [NB*BCAP]
    int* gcursor  = (int*)(pairBuf + (size_t)NB * BCAP);   // [NB*GC_STRIDE] padded

    // ---- zero the padded per-bucket cursors ----
    hipMemsetAsync(gcursor, 0, NB * GC_STRIDE * sizeof(int), stream);

    // ---- fused init + edge binning (bucket blocks first) ----
    init_bucket_kernel<<<GRID_IB, 256, 0, stream>>>(
        x, W1, W2, Wo, ei, xb, A + (size_t)N_NODES * IN_DIM, Wp, out, gcursor, pairBuf);

    // ---- fused CSR-in-LDS + gather aggregate ----
    aggB_kernel<<<NB, AGG_THREADS, 0, stream>>>(pairBuf, gcursor, xb, A);

    // ---- fused MLP + pool (v2 core frozen; low-atomic epilogue) ----
    mlp_fused<<<M_PAD / 32, 64, 0, stream>>>(A, Wp, b1, b2, bo, out, bi);
}

// Round 12
// 289.858 us; speedup vs baseline: 1.0082x; 1.0082x over previous
//
#include <hip/hip_runtime.h>

#define N_NODES  100000
#define M_PAD    100096   // 782 * 128
#define N_EDGES  1600000
#define N_GRAPHS 512
#define IN_DIM   128
#define HID_DIM  256
#define OUT_DIM  128

#define NB       782      // buckets of 128 nodes
#define BCAP     3072     // mean 2048, +22 sigma headroom
#define CHUNK    16384    // edges per bucket block
#define BKB      ((N_EDGES + CHUNK - 1) / CHUNK)   // 98
#define GC_STRIDE 16      // gcursor padded to one counter per 64B line

typedef __bf16 bf16x8 __attribute__((ext_vector_type(8)));
typedef __bf16 bf16x4 __attribute__((ext_vector_type(4)));
typedef __bf16 bf16x2 __attribute__((ext_vector_type(2)));
typedef float  f32x4  __attribute__((ext_vector_type(4)));

// ---- packed weight buffer layout (frag-ordered, LINEAR group stream) ----
#define WP_L2_BASE 32768
#define WP_L3_BASE 98304
#define WP_TOTAL   131072

// ---- fused init+bucket grid ----
#define R_X    (N_NODES * IN_DIM / 4)
#define R_APAD ((M_PAD - N_NODES) * IN_DIM / 4)
#define R_WP   WP_TOTAL
#define R_OUT  (N_GRAPHS * OUT_DIM / 4)
#define R_TOTAL (R_X + R_APAD + R_WP + R_OUT)
#define NIB    2048       // v13: grid-stride init blocks (was 13088 one-shot
                          // blocks; ~1-2us lifetime x dispatch rate => only a
                          // few dozen wgs in flight => 900 GB/s, Occ 16%.
                          // 2048 persistent blocks give ~6.4 items/thread.)
#define GRID_IB (BKB + NIB)

// ---------------- fused init + edge binning ----------------
__global__ __launch_bounds__(256) void init_bucket_kernel(const float* __restrict__ x,
                                                          const float* __restrict__ W1,
                                                          const float* __restrict__ W2,
                                                          const float* __restrict__ Wo,
                                                          const int* __restrict__ ei,
                                                          __bf16* __restrict__ xb,
                                                          __bf16* __restrict__ Apad,
                                                          __bf16* __restrict__ Wp,
                                                          float* __restrict__ outbuf,
                                                          int* __restrict__ gcursor,
                                                          unsigned* __restrict__ pairBuf) {
    __shared__ int lcnt[NB];
    __shared__ int lbase[NB];
    const int tid = threadIdx.x;

    if (blockIdx.x < BKB) {
        // ---- bucket path ----
        const int e0 = blockIdx.x * CHUNK;

        for (int b = tid; b < NB; b += 256) lcnt[b] = 0;
        __syncthreads();

        for (int i = tid; i < CHUNK; i += 256) {
            int e = e0 + i;
            if (e < N_EDGES) atomicAdd(&lcnt[ei[N_EDGES + e] >> 7], 1);
        }
        __syncthreads();

        for (int b = tid; b < NB; b += 256) {
            int c = lcnt[b];
            lbase[b] = c ? atomicAdd(&gcursor[b * GC_STRIDE], c) : 0;
            lcnt[b] = 0;
        }
        __syncthreads();

        for (int i = tid; i < CHUNK; i += 256) {
            int e = e0 + i;
            if (e < N_EDGES) {
                int s = ei[e];
                int d = ei[N_EDGES + e];
                int b = d >> 7;
                int pos = lbase[b] + atomicAdd(&lcnt[b], 1);
                if (pos < BCAP)
                    pairBuf[(size_t)b * BCAP + pos] = (unsigned)s | ((unsigned)(d & 127) << 17);
            }
        }
        return;
    }

    // ---- init path: grid-stride over the work-item space ----
    const long long stride = (long long)NIB * 256;
    for (long long i0 = (long long)(blockIdx.x - BKB) * 256 + tid; i0 < R_TOTAL; i0 += stride) {
        long long i = i0;
        if (i < R_X) {
            float4 v = ((const float4*)x)[i];
            bf16x4 h;
            h.x = (__bf16)v.x; h.y = (__bf16)v.y; h.z = (__bf16)v.z; h.w = (__bf16)v.w;
            ((bf16x4*)xb)[i] = h;
            continue;
        }
        i -= R_X;
        if (i < R_APAD) {
            bf16x4 z; z.x = (__bf16)0.f; z.y = (__bf16)0.f; z.z = (__bf16)0.f; z.w = (__bf16)0.f;
            ((bf16x4*)Apad)[i] = z;
            continue;
        }
        i -= R_APAD;
        if (i < R_WP) {
            int idx = (int)i;
            const float* src;
            int K, Nn, base;
            if (idx < WP_L2_BASE)      { src = W1; K = 128; Nn = 256; base = 0; }
            else if (idx < WP_L3_BASE) { src = W2; K = 256; Nn = 256; base = WP_L2_BASE; }
            else                       { src = Wo; K = 256; Nn = 128; base = WP_L3_BASE; }
            int r0 = idx - base;
            int slabElems = 32 * K;          // power of two
            int j = r0 / slabElems;
            int r = r0 % slabElems;
            int KS = K / 32;
            int p = r >> 9;
            int lane = (r >> 3) & 63;
            int e = r & 7;
            int s = p % KS, t = p / KS;
            int quad = lane >> 4, l16 = lane & 15;
            int n = j * 32 + t * 16 + l16;
            int k = s * 32 + quad * 8 + e;
            Wp[idx] = (__bf16)src[(size_t)k * Nn + n];
            continue;
        }
        i -= R_WP;
        if (i < R_OUT) {
            ((float4*)outbuf)[i] = make_float4(0.f, 0.f, 0.f, 0.f);
        }
    }
}

// ---------------- aggB: fused per-bucket CSR build (LDS) + gather aggregate ----------------
#define AGG_THREADS 512

__global__ __launch_bounds__(AGG_THREADS) void aggB_kernel(const unsigned* __restrict__ pairBuf,
                                                           const int* __restrict__ gcursor,
                                                           const __bf16* __restrict__ xb,
                                                           __bf16* __restrict__ A) {
    __shared__ int lcnt[128];
    __shared__ int loffs[128];
    __shared__ int lcur[128];
    __shared__ int offx[128];
    __shared__ unsigned sorted[BCAP];   // 12 KB

    const int b = blockIdx.x;
    const int tid = threadIdx.x;
    const int node0 = b << 7;
    const int cnt = min(gcursor[b * GC_STRIDE], BCAP);
    const unsigned* pb = pairBuf + (size_t)b * BCAP;

    if (tid < 128) { lcnt[tid] = 0; lcur[tid] = 0; }
    __syncthreads();

    for (int i = tid; i < cnt; i += AGG_THREADS)
        atomicAdd(&lcnt[pb[i] >> 17], 1);
    __syncthreads();

    if (tid < 128) loffs[tid] = lcnt[tid];
    __syncthreads();
    for (int st = 1; st < 128; st <<= 1) {
        int add = (tid < 128 && tid >= st) ? loffs[tid - st] : 0;
        __syncthreads();
        if (tid < 128) loffs[tid] += add;
        __syncthreads();
    }
    if (tid < 128) offx[tid] = loffs[tid] - lcnt[tid];
    __syncthreads();

    for (int i = tid; i < cnt; i += AGG_THREADS) {
        unsigned u = pb[i];
        int dl = u >> 17;
        int slot = atomicAdd(&lcur[dl], 1);
        sorted[offx[dl] + slot] = u & 0x1FFFF;
    }
    __syncthreads();

    // ---- phase 2: 8 waves x 16 nodes, register-accumulated gather ----
    const int wid = tid >> 6;
    const int lane = tid & 63;
    const int c0 = lane * 2;

    #pragma unroll 1
    for (int n = wid; n < 128; n += (AGG_THREADS / 64)) {
        int v = node0 + n;
        if (v >= N_NODES) break;            // wave-uniform; later n only larger
        int off = offx[n];
        int len = lcnt[n];
        bf16x2 self = *(const bf16x2*)(xb + (size_t)v * IN_DIM + c0);
        float ax = (float)self.x, ay = (float)self.y;

        int addr = off + lane;
        if (addr >= cnt) addr = (cnt > 0) ? cnt - 1 : 0;
        int myidx = (int)sorted[addr];

        int lim = len < 64 ? len : 64;
        int j = 0;
        for (; j + 8 <= lim; j += 8) {
            int s0 = __shfl(myidx, j + 0, 64);
            int s1 = __shfl(myidx, j + 1, 64);
            int s2 = __shfl(myidx, j + 2, 64);
            int s3 = __shfl(myidx, j + 3, 64);
            int s4 = __shfl(myidx, j + 4, 64);
            int s5 = __shfl(myidx, j + 5, 64);
            int s6 = __shfl(myidx, j + 6, 64);
            int s7 = __shfl(myidx, j + 7, 64);
            bf16x2 v0 = *(const bf16x2*)(xb + (size_t)s0 * IN_DIM + c0);
            bf16x2 v1 = *(const bf16x2*)(xb + (size_t)s1 * IN_DIM + c0);
            bf16x2 v2 = *(const bf16x2*)(xb + (size_t)s2 * IN_DIM + c0);
            bf16x2 v3 = *(const bf16x2*)(xb + (size_t)s3 * IN_DIM + c0);
            bf16x2 v4 = *(const bf16x2*)(xb + (size_t)s4 * IN_DIM + c0);
            bf16x2 v5 = *(const bf16x2*)(xb + (size_t)s5 * IN_DIM + c0);
            bf16x2 v6 = *(const bf16x2*)(xb + (size_t)s6 * IN_DIM + c0);
            bf16x2 v7 = *(const bf16x2*)(xb + (size_t)s7 * IN_DIM + c0);
            ax += (float)v0.x + (float)v1.x + (float)v2.x + (float)v3.x
                + (float)v4.x + (float)v5.x + (float)v6.x + (float)v7.x;
            ay += (float)v0.y + (float)v1.y + (float)v2.y + (float)v3.y
                + (float)v4.y + (float)v5.y + (float)v6.y + (float)v7.y;
        }
        for (; j < lim; ++j) {
            int s = __shfl(myidx, j, 64);
            bf16x2 vv = *(const bf16x2*)(xb + (size_t)s * IN_DIM + c0);
            ax += (float)vv.x;
            ay += (float)vv.y;
        }
        for (; j < len; ++j) {
            int s = (int)sorted[off + j];
            bf16x2 vv = *(const bf16x2*)(xb + (size_t)s * IN_DIM + c0);
            ax += (float)vv.x;
            ay += (float)vv.y;
        }
        bf16x2 h;
        h.x = (__bf16)ax;
        h.y = (__bf16)ay;
        *(bf16x2*)(A + (size_t)v * IN_DIM + c0) = h;
    }
}

// ---------------- fused 3-layer MLP + pool (v2 core FROZEN; epilogue v11) ----------------
__device__ __forceinline__ void load_group_p(const __bf16* __restrict__ p, int lane,
                                             bf16x8* __restrict__ dst) {
    #pragma unroll
    for (int e = 0; e < 8; ++e)
        dst[e] = *(const bf16x8*)(p + (e * 64 + lane) * 8);
}

__device__ __forceinline__ void store_H(__bf16* __restrict__ H, int j, int quad, int l16,
                                        const f32x4 (&acc)[2][2], float bt0, float bt1) {
    const int c7 = l16 & 7;
    const int ch = l16 >> 3;
    #pragma unroll
    for (int i = 0; i < 2; ++i)
        #pragma unroll
        for (int t = 0; t < 2; ++t) {
            const float bb = t ? bt1 : bt0;
            #pragma unroll
            for (int rr = 0; rr < 4; ++rr) {
                int row = i * 16 + quad * 4 + rr;
                int cidx = (j * 4 + t * 2 + ch + row) & 31;
                float v = fmaxf(acc[i][t][rr] + bb, 0.f);
                H[row * 256 + cidx * 8 + c7] = (__bf16)v;
            }
        }
}

__global__ __launch_bounds__(64) void mlp_fused(const __bf16* __restrict__ A,
                                                const __bf16* __restrict__ Wp,
                                                const float* __restrict__ b1,
                                                const float* __restrict__ b2,
                                                const float* __restrict__ bo,
                                                float* __restrict__ out,
                                                const int* __restrict__ batch) {
    __shared__ __bf16 H[32 * 256];   // 16 KB

    const int lane = threadIdx.x;
    const int quad = lane >> 4, l16 = lane & 15;
    const size_t mblk = (size_t)blockIdx.x * 32;
    const int r0g = (int)mblk;

    bf16x8 a[2][8];
    bf16x8 buf0[8];
    bf16x8 buf1[8];

    const __bf16* wp = Wp;
    load_group_p(wp, lane, buf0);    // group 0

    // layer-1 A-frags
    #pragma unroll
    for (int i = 0; i < 2; ++i)
        #pragma unroll
        for (int s = 0; s < 4; ++s)
            a[i][s] = *(const bf16x8*)(A + (mblk + i * 16 + l16) * IN_DIM + s * 32 + quad * 8);

    // ---- layer 1: groups 0..7 ----
    #pragma unroll 1
    for (int j = 0; j < 8; j += 2) {
        {
            load_group_p(wp + 4096, lane, buf1);
            float bt0 = b1[j * 32 + l16];
            float bt1 = b1[j * 32 + 16 + l16];
            f32x4 acc[2][2] = {};
            #pragma unroll
            for (int p = 0; p < 8; ++p) {
                const int t = p >> 2, s = p & 3;
                acc[0][t] = __builtin_amdgcn_mfma_f32_16x16x32_bf16(a[0][s], buf0[p], acc[0][t], 0, 0, 0);
                acc[1][t] = __builtin_amdgcn_mfma_f32_16x16x32_bf16(a[1][s], buf0[p], acc[1][t], 0, 0, 0);
            }
            store_H(H, j, quad, l16, acc, bt0, bt1);
        }
        {
            load_group_p(wp + 8192, lane, buf0);
            float bt0 = b1[(j + 1) * 32 + l16];
            float bt1 = b1[(j + 1) * 32 + 16 + l16];
            f32x4 acc[2][2] = {};
            #pragma unroll
            for (int p = 0; p < 8; ++p) {
                const int t = p >> 2, s = p & 3;
                acc[0][t] = __builtin_amdgcn_mfma_f32_16x16x32_bf16(a[0][s], buf1[p], acc[0][t], 0, 0, 0);
                acc[1][t] = __builtin_amdgcn_mfma_f32_16x16x32_bf16(a[1][s], buf1[p], acc[1][t], 0, 0, 0);
            }
            store_H(H, j + 1, quad, l16, acc, bt0, bt1);
        }
        wp += 8192;
    }
    __syncthreads();

    // ---- layer 2 A-frags from LDS ----
    #pragma unroll
    for (int i = 0; i < 2; ++i)
        #pragma unroll
        for (int s = 0; s < 8; ++s) {
            int row = i * 16 + l16;
            a[i][s] = *(const bf16x8*)(H + row * 256 + (((s * 4 + quad) + row) & 31) * 8);
        }
    __syncthreads();

    // ---- layer 2: groups 8..23 ----
    #pragma unroll 1
    for (int j = 0; j < 8; ++j) {
        load_group_p(wp + 4096, lane, buf1);
        float bt0 = b2[j * 32 + l16];
        float bt1 = b2[j * 32 + 16 + l16];
        f32x4 acc[2][2] = {};
        #pragma unroll
        for (int p = 0; p < 8; ++p) {
            acc[0][0] = __builtin_amdgcn_mfma_f32_16x16x32_bf16(a[0][p], buf0[p], acc[0][0], 0, 0, 0);
            acc[1][0] = __builtin_amdgcn_mfma_f32_16x16x32_bf16(a[1][p], buf0[p], acc[1][0], 0, 0, 0);
        }
        load_group_p(wp + 8192, lane, buf0);
        #pragma unroll
        for (int p = 0; p < 8; ++p) {
            acc[0][1] = __builtin_amdgcn_mfma_f32_16x16x32_bf16(a[0][p], buf1[p], acc[0][1], 0, 0, 0);
            acc[1][1] = __builtin_amdgcn_mfma_f32_16x16x32_bf16(a[1][p], buf1[p], acc[1][1], 0, 0, 0);
        }
        store_H(H, j, quad, l16, acc, bt0, bt1);
        wp += 8192;
    }
    __syncthreads();

    // ---- layer 3 A-frags from LDS ----
    #pragma unroll
    for (int i = 0; i < 2; ++i)
        #pragma unroll
        for (int s = 0; s < 8; ++s) {
            int row = i * 16 + l16;
            a[i][s] = *(const bf16x8*)(H + row * 256 + (((s * 4 + quad) + row) & 31) * 8);
        }

    // ---- epilogue metadata (once): tile graph range + per-row graph ids ----
    const bool fulltile = (r0g + 31 < N_NODES);
    int gfirst = (r0g < N_NODES) ? batch[r0g] : -1;
    int glastE = -2;
    if (r0g < N_NODES) {
        int mlast = r0g + 31;
        if (mlast >= N_NODES) mlast = N_NODES - 1;
        glastE = batch[mlast];
    }
    int gm[2][4];
    #pragma unroll
    for (int i = 0; i < 2; ++i)
        #pragma unroll
        for (int rr = 0; rr < 4; ++rr) {
            int m = r0g + i * 16 + quad * 4 + rr;
            gm[i][rr] = (m < N_NODES) ? batch[m] : -1;
        }
    const bool fast = fulltile && (gfirst == glastE);

    // ---- layer 3: groups 24..31 (4 slabs), pooled atomic output ----
    #pragma unroll 1
    for (int j = 0; j < 4; ++j) {
        load_group_p(wp + 4096, lane, buf1);
        float bt0 = bo[j * 32 + l16];
        float bt1 = bo[j * 32 + 16 + l16];
        f32x4 acc[2][2] = {};
        #pragma unroll
        for (int p = 0; p < 8; ++p) {
            acc[0][0] = __builtin_amdgcn_mfma_f32_16x16x32_bf16(a[0][p], buf0[p], acc[0][0], 0, 0, 0);
            acc[1][0] = __builtin_amdgcn_mfma_f32_16x16x32_bf16(a[1][p], buf0[p], acc[1][0], 0, 0, 0);
        }
        load_group_p(wp + 8192, lane, buf0);  // last iter reads past Wp into pairBuf (harmless)
        #pragma unroll
        for (int p = 0; p < 8; ++p) {
            acc[0][1] = __builtin_amdgcn_mfma_f32_16x16x32_bf16(a[0][p], buf1[p], acc[0][1], 0, 0, 0);
            acc[1][1] = __builtin_amdgcn_mfma_f32_16x16x32_bf16(a[1][p], buf1[p], acc[1][1], 0, 0, 0);
        }

        if (fast) {
            #pragma unroll
            for (int t = 0; t < 2; ++t) {
                float sum = 0.f;
                #pragma unroll
                for (int i = 0; i < 2; ++i)
                    #pragma unroll
                    for (int rr = 0; rr < 4; ++rr) sum += acc[i][t][rr];
                sum += __shfl_xor(sum, 16, 64);
                sum += __shfl_xor(sum, 32, 64);
                if (quad == 0) {
                    int c = j * 32 + t * 16 + l16;
                    float bb = t ? bt1 : bt0;
                    atomicAdd(out + (size_t)gfirst * OUT_DIM + c, sum + 32.f * bb);
                }
            }
        } else {
            // per-graph masked reduction: one atomic per col per graph
            #pragma unroll 1
            for (int dg = gfirst; dg <= glastE; ++dg) {
                float cntv = 0.f;
                #pragma unroll
                for (int i = 0; i < 2; ++i)
                    #pragma unroll
                    for (int rr = 0; rr < 4; ++rr)
                        if (gm[i][rr] == dg) cntv += 1.f;
                cntv += __shfl_xor(cntv, 16, 64);
                cntv += __shfl_xor(cntv, 32, 64);
                #pragma unroll
                for (int t = 0; t < 2; ++t) {
                    float s = 0.f;
                    #pragma unroll
                    for (int i = 0; i < 2; ++i)
                        #pragma unroll
                        for (int rr = 0; rr < 4; ++rr)
                            if (gm[i][rr] == dg) s += acc[i][t][rr];
                    s += __shfl_xor(s, 16, 64);
                    s += __shfl_xor(s, 32, 64);
                    if (quad == 0) {
                        int c = j * 32 + t * 16 + l16;
                        float bb = t ? bt1 : bt0;
                        atomicAdd(out + (size_t)dg * OUT_DIM + c, s + cntv * bb);
                    }
                }
            }
        }
        wp += 8192;
    }
}

extern "C" void kernel_launch(void* const* d_in, const int* in_sizes, int n_in,
                              void* d_out, int out_size, void* d_ws, size_t ws_size,
                              hipStream_t stream) {
    const float* x  = (const float*)d_in[0];
    const int*   ei = (const int*)d_in[1];
    const int*   bi = (const int*)d_in[2];
    const float* W1 = (const float*)d_in[3];
    const float* b1 = (const float*)d_in[4];
    const float* W2 = (const float*)d_in[5];
    const float* b2 = (const float*)d_in[6];
    const float* Wo = (const float*)d_in[7];
    const float* bo = (const float*)d_in[8];
    float* out = (float*)d_out;

    __bf16* A  = (__bf16*)d_ws;                        // [M_PAD][128]
    __bf16* xb = A + (size_t)M_PAD * IN_DIM;           // [N_NODES][128]
    __bf16* Wp = xb + (size_t)N_NODES * IN_DIM;        // [131072] packed frag-ordered
    unsigned* pairBuf = (unsigned*)(Wp + WP_TOTAL);    // [NB*BCAP]
    int* gcursor  = (int*)(pairBuf + (size_t)NB * BCAP);   // [NB*GC_STRIDE] padded

    // ---- zero the padded per-bucket cursors ----
    hipMemsetAsync(gcursor, 0, NB * GC_STRIDE * sizeof(int), stream);

    // ---- fused init + edge binning (bucket blocks first, grid-stride init) ----
    init_bucket_kernel<<<GRID_IB, 256, 0, stream>>>(
        x, W1, W2, Wo, ei, xb, A + (size_t)N_NODES * IN_DIM, Wp, out, gcursor, pairBuf);

    // ---- fused CSR-in-LDS + gather aggregate ----
    aggB_kernel<<<NB, AGG_THREADS, 0, stream>>>(pairBuf, gcursor, xb, A);

    // ---- fused MLP + pool (v2 core frozen; low-atomic epilogue) ----
    mlp_fused<<<M_PAD / 32, 64, 0, stream>>>(A, Wp, b1, b2, bo, out, bi);
}

// Round 13
// 258.162 us; speedup vs baseline: 1.1319x; 1.1228x over previous
//
#include <hip/hip_runtime.h>

#define N_NODES  100000
#define M_PAD    100096   // 782 * 128
#define N_EDGES  1600000
#define N_GRAPHS 512
#define IN_DIM   128
#define HID_DIM  256
#define OUT_DIM  128

#define NB       782      // buckets of 128 nodes
#define BCAP     3072     // mean 2048, +22 sigma headroom
#define CHUNK    4096     // v14: 391 bucket blocks — scatter line-traffic ~half
                          // of CHUNK=2048, parallelism ~4x of CHUNK=16384
#define BKB      ((N_EDGES + CHUNK - 1) / CHUNK)   // 391
#define GC_STRIDE 16      // gcursor padded to one counter per 64B line

typedef __bf16 bf16x8 __attribute__((ext_vector_type(8)));
typedef __bf16 bf16x4 __attribute__((ext_vector_type(4)));
typedef __bf16 bf16x2 __attribute__((ext_vector_type(2)));
typedef float  f32x4  __attribute__((ext_vector_type(4)));

// ---- packed weight buffer layout (frag-ordered, LINEAR group stream) ----
#define WP_L2_BASE 32768
#define WP_L3_BASE 98304
#define WP_TOTAL   131072

// ---- fused init+bucket grid ----
// All region sizes are multiples of 1024 -> each 1024-item block lies in ONE
// region: branch once per block, 4 independent float4 ops per thread (4x MLP).
#define R_X    (N_NODES * IN_DIM / 4)                  // 3200000
#define R_APAD ((M_PAD - N_NODES) * IN_DIM / 4)        // 3072
#define R_WP   WP_TOTAL                                // 131072
#define R_OUT  (N_GRAPHS * OUT_DIM / 4)                // 16384
#define R_TOTAL (R_X + R_APAD + R_WP + R_OUT)          // 3350528
#define NI4    (R_TOTAL / 1024)                        // 3272
#define GRID_IB (BKB + NI4)

// ---------------- fused init + edge binning ----------------
__global__ __launch_bounds__(256) void init_bucket_kernel(const float* __restrict__ x,
                                                          const float* __restrict__ W1,
                                                          const float* __restrict__ W2,
                                                          const float* __restrict__ Wo,
                                                          const int* __restrict__ ei,
                                                          __bf16* __restrict__ xb,
                                                          __bf16* __restrict__ Apad,
                                                          __bf16* __restrict__ Wp,
                                                          float* __restrict__ outbuf,
                                                          int* __restrict__ gcursor,
                                                          unsigned* __restrict__ pairBuf) {
    __shared__ int lcnt[NB];
    __shared__ int lbase[NB];
    const int tid = threadIdx.x;

    if (blockIdx.x < BKB) {
        // ---- bucket path ----
        const int e0 = blockIdx.x * CHUNK;

        for (int b = tid; b < NB; b += 256) lcnt[b] = 0;
        __syncthreads();

        for (int i = tid; i < CHUNK; i += 256) {
            int e = e0 + i;
            if (e < N_EDGES) atomicAdd(&lcnt[ei[N_EDGES + e] >> 7], 1);
        }
        __syncthreads();

        for (int b = tid; b < NB; b += 256) {
            int c = lcnt[b];
            lbase[b] = c ? atomicAdd(&gcursor[b * GC_STRIDE], c) : 0;
            lcnt[b] = 0;
        }
        __syncthreads();

        for (int i = tid; i < CHUNK; i += 256) {
            int e = e0 + i;
            if (e < N_EDGES) {
                int s = ei[e];
                int d = ei[N_EDGES + e];
                int b = d >> 7;
                int pos = lbase[b] + atomicAdd(&lcnt[b], 1);
                if (pos < BCAP)
                    pairBuf[(size_t)b * BCAP + pos] = (unsigned)s | ((unsigned)(d & 127) << 17);
            }
        }
        return;
    }

    // ---- init path: block-uniform region, 4 consecutive float4s per thread ----
    const long long base = (long long)(blockIdx.x - BKB) * 1024;
    const long long i = base + tid * 4;

    if (base < R_X) {
        #pragma unroll
        for (int u = 0; u < 4; ++u) {
            float4 v = ((const float4*)x)[i + u];
            bf16x4 h;
            h.x = (__bf16)v.x; h.y = (__bf16)v.y; h.z = (__bf16)v.z; h.w = (__bf16)v.w;
            ((bf16x4*)xb)[i + u] = h;
        }
        return;
    }
    if (base < R_X + R_APAD) {
        long long r = i - R_X;
        bf16x4 z; z.x = (__bf16)0.f; z.y = (__bf16)0.f; z.z = (__bf16)0.f; z.w = (__bf16)0.f;
        #pragma unroll
        for (int u = 0; u < 4; ++u)
            ((bf16x4*)Apad)[r + u] = z;
        return;
    }
    if (base < R_X + R_APAD + R_WP) {
        int idx0 = (int)(i - R_X - R_APAD);
        #pragma unroll
        for (int u = 0; u < 4; ++u) {
            int idx = idx0 + u;
            const float* src;
            int K, Nn, bas;
            if (idx < WP_L2_BASE)      { src = W1; K = 128; Nn = 256; bas = 0; }
            else if (idx < WP_L3_BASE) { src = W2; K = 256; Nn = 256; bas = WP_L2_BASE; }
            else                       { src = Wo; K = 256; Nn = 128; bas = WP_L3_BASE; }
            int r0 = idx - bas;
            int slabElems = 32 * K;          // power of two
            int j = r0 / slabElems;
            int r = r0 % slabElems;
            int KS = K / 32;
            int p = r >> 9;
            int lane = (r >> 3) & 63;
            int e = r & 7;
            int s = p % KS, t = p / KS;
            int quad = lane >> 4, l16 = lane & 15;
            int n = j * 32 + t * 16 + l16;
            int k = s * 32 + quad * 8 + e;
            Wp[idx] = (__bf16)src[(size_t)k * Nn + n];
        }
        return;
    }
    {
        long long r = i - R_X - R_APAD - R_WP;
        float4 z = make_float4(0.f, 0.f, 0.f, 0.f);
        #pragma unroll
        for (int u = 0; u < 4; ++u)
            ((float4*)outbuf)[r + u] = z;
    }
}

// ---------------- aggB: fused per-bucket CSR build (LDS) + gather aggregate ----------------
#define AGG_THREADS 512

__global__ __launch_bounds__(AGG_THREADS) void aggB_kernel(const unsigned* __restrict__ pairBuf,
                                                           const int* __restrict__ gcursor,
                                                           const __bf16* __restrict__ xb,
                                                           __bf16* __restrict__ A) {
    __shared__ int lcnt[128];
    __shared__ int loffs[128];
    __shared__ int lcur[128];
    __shared__ int offx[128];
    __shared__ unsigned sorted[BCAP];   // 12 KB

    const int b = blockIdx.x;
    const int tid = threadIdx.x;
    const int node0 = b << 7;
    const int cnt = min(gcursor[b * GC_STRIDE], BCAP);
    const unsigned* pb = pairBuf + (size_t)b * BCAP;

    if (tid < 128) { lcnt[tid] = 0; lcur[tid] = 0; }
    __syncthreads();

    for (int i = tid; i < cnt; i += AGG_THREADS)
        atomicAdd(&lcnt[pb[i] >> 17], 1);
    __syncthreads();

    if (tid < 128) loffs[tid] = lcnt[tid];
    __syncthreads();
    for (int st = 1; st < 128; st <<= 1) {
        int add = (tid < 128 && tid >= st) ? loffs[tid - st] : 0;
        __syncthreads();
        if (tid < 128) loffs[tid] += add;
        __syncthreads();
    }
    if (tid < 128) offx[tid] = loffs[tid] - lcnt[tid];
    __syncthreads();

    for (int i = tid; i < cnt; i += AGG_THREADS) {
        unsigned u = pb[i];
        int dl = u >> 17;
        int slot = atomicAdd(&lcur[dl], 1);
        sorted[offx[dl] + slot] = u & 0x1FFFF;
    }
    __syncthreads();

    // ---- phase 2: 8 waves x 16 nodes, register-accumulated gather ----
    const int wid = tid >> 6;
    const int lane = tid & 63;
    const int c0 = lane * 2;

    #pragma unroll 1
    for (int n = wid; n < 128; n += (AGG_THREADS / 64)) {
        int v = node0 + n;
        if (v >= N_NODES) break;            // wave-uniform; later n only larger
        int off = offx[n];
        int len = lcnt[n];
        bf16x2 self = *(const bf16x2*)(xb + (size_t)v * IN_DIM + c0);
        float ax = (float)self.x, ay = (float)self.y;

        int addr = off + lane;
        if (addr >= cnt) addr = (cnt > 0) ? cnt - 1 : 0;
        int myidx = (int)sorted[addr];

        int lim = len < 64 ? len : 64;
        int j = 0;
        for (; j + 8 <= lim; j += 8) {
            int s0 = __shfl(myidx, j + 0, 64);
            int s1 = __shfl(myidx, j + 1, 64);
            int s2 = __shfl(myidx, j + 2, 64);
            int s3 = __shfl(myidx, j + 3, 64);
            int s4 = __shfl(myidx, j + 4, 64);
            int s5 = __shfl(myidx, j + 5, 64);
            int s6 = __shfl(myidx, j + 6, 64);
            int s7 = __shfl(myidx, j + 7, 64);
            bf16x2 v0 = *(const bf16x2*)(xb + (size_t)s0 * IN_DIM + c0);
            bf16x2 v1 = *(const bf16x2*)(xb + (size_t)s1 * IN_DIM + c0);
            bf16x2 v2 = *(const bf16x2*)(xb + (size_t)s2 * IN_DIM + c0);
            bf16x2 v3 = *(const bf16x2*)(xb + (size_t)s3 * IN_DIM + c0);
            bf16x2 v4 = *(const bf16x2*)(xb + (size_t)s4 * IN_DIM + c0);
            bf16x2 v5 = *(const bf16x2*)(xb + (size_t)s5 * IN_DIM + c0);
            bf16x2 v6 = *(const bf16x2*)(xb + (size_t)s6 * IN_DIM + c0);
            bf16x2 v7 = *(const bf16x2*)(xb + (size_t)s7 * IN_DIM + c0);
            ax += (float)v0.x + (float)v1.x + (float)v2.x + (float)v3.x
                + (float)v4.x + (float)v5.x + (float)v6.x + (float)v7.x;
            ay += (float)v0.y + (float)v1.y + (float)v2.y + (float)v3.y
                + (float)v4.y + (float)v5.y + (float)v6.y + (float)v7.y;
        }
        for (; j < lim; ++j) {
            int s = __shfl(myidx, j, 64);
            bf16x2 vv = *(const bf16x2*)(xb + (size_t)s * IN_DIM + c0);
            ax += (float)vv.x;
            ay += (float)vv.y;
        }
        for (; j < len; ++j) {
            int s = (int)sorted[off + j];
            bf16x2 vv = *(const bf16x2*)(xb + (size_t)s * IN_DIM + c0);
            ax += (float)vv.x;
            ay += (float)vv.y;
        }
        bf16x2 h;
        h.x = (__bf16)ax;
        h.y = (__bf16)ay;
        *(bf16x2*)(A + (size_t)v * IN_DIM + c0) = h;
    }
}

// ---------------- fused 3-layer MLP + pool (v2 core FROZEN; epilogue v11) ----------------
__device__ __forceinline__ void load_group_p(const __bf16* __restrict__ p, int lane,
                                             bf16x8* __restrict__ dst) {
    #pragma unroll
    for (int e = 0; e < 8; ++e)
        dst[e] = *(const bf16x8*)(p + (e * 64 + lane) * 8);
}

__device__ __forceinline__ void store_H(__bf16* __restrict__ H, int j, int quad, int l16,
                                        const f32x4 (&acc)[2][2], float bt0, float bt1) {
    const int c7 = l16 & 7;
    const int ch = l16 >> 3;
    #pragma unroll
    for (int i = 0; i < 2; ++i)
        #pragma unroll
        for (int t = 0; t < 2; ++t) {
            const float bb = t ? bt1 : bt0;
            #pragma unroll
            for (int rr = 0; rr < 4; ++rr) {
                int row = i * 16 + quad * 4 + rr;
                int cidx = (j * 4 + t * 2 + ch + row) & 31;
                float v = fmaxf(acc[i][t][rr] + bb, 0.f);
                H[row * 256 + cidx * 8 + c7] = (__bf16)v;
            }
        }
}

__global__ __launch_bounds__(64) void mlp_fused(const __bf16* __restrict__ A,
                                                const __bf16* __restrict__ Wp,
                                                const float* __restrict__ b1,
                                                const float* __restrict__ b2,
                                                const float* __restrict__ bo,
                                                float* __restrict__ out,
                                                const int* __restrict__ batch) {
    __shared__ __bf16 H[32 * 256];   // 16 KB

    const int lane = threadIdx.x;
    const int quad = lane >> 4, l16 = lane & 15;
    const size_t mblk = (size_t)blockIdx.x * 32;
    const int r0g = (int)mblk;

    bf16x8 a[2][8];
    bf16x8 buf0[8];
    bf16x8 buf1[8];

    const __bf16* wp = Wp;
    load_group_p(wp, lane, buf0);    // group 0

    // layer-1 A-frags
    #pragma unroll
    for (int i = 0; i < 2; ++i)
        #pragma unroll
        for (int s = 0; s < 4; ++s)
            a[i][s] = *(const bf16x8*)(A + (mblk + i * 16 + l16) * IN_DIM + s * 32 + quad * 8);

    // ---- layer 1: groups 0..7 ----
    #pragma unroll 1
    for (int j = 0; j < 8; j += 2) {
        {
            load_group_p(wp + 4096, lane, buf1);
            float bt0 = b1[j * 32 + l16];
            float bt1 = b1[j * 32 + 16 + l16];
            f32x4 acc[2][2] = {};
            #pragma unroll
            for (int p = 0; p < 8; ++p) {
                const int t = p >> 2, s = p & 3;
                acc[0][t] = __builtin_amdgcn_mfma_f32_16x16x32_bf16(a[0][s], buf0[p], acc[0][t], 0, 0, 0);
                acc[1][t] = __builtin_amdgcn_mfma_f32_16x16x32_bf16(a[1][s], buf0[p], acc[1][t], 0, 0, 0);
            }
            store_H(H, j, quad, l16, acc, bt0, bt1);
        }
        {
            load_group_p(wp + 8192, lane, buf0);
            float bt0 = b1[(j + 1) * 32 + l16];
            float bt1 = b1[(j + 1) * 32 + 16 + l16];
            f32x4 acc[2][2] = {};
            #pragma unroll
            for (int p = 0; p < 8; ++p) {
                const int t = p >> 2, s = p & 3;
                acc[0][t] = __builtin_amdgcn_mfma_f32_16x16x32_bf16(a[0][s], buf1[p], acc[0][t], 0, 0, 0);
                acc[1][t] = __builtin_amdgcn_mfma_f32_16x16x32_bf16(a[1][s], buf1[p], acc[1][t], 0, 0, 0);
            }
            store_H(H, j + 1, quad, l16, acc, bt0, bt1);
        }
        wp += 8192;
    }
    __syncthreads();

    // ---- layer 2 A-frags from LDS ----
    #pragma unroll
    for (int i = 0; i < 2; ++i)
        #pragma unroll
        for (int s = 0; s < 8; ++s) {
            int row = i * 16 + l16;
            a[i][s] = *(const bf16x8*)(H + row * 256 + (((s * 4 + quad) + row) & 31) * 8);
        }
    __syncthreads();

    // ---- layer 2: groups 8..23 ----
    #pragma unroll 1
    for (int j = 0; j < 8; ++j) {
        load_group_p(wp + 4096, lane, buf1);
        float bt0 = b2[j * 32 + l16];
        float bt1 = b2[j * 32 + 16 + l16];
        f32x4 acc[2][2] = {};
        #pragma unroll
        for (int p = 0; p < 8; ++p) {
            acc[0][0] = __builtin_amdgcn_mfma_f32_16x16x32_bf16(a[0][p], buf0[p], acc[0][0], 0, 0, 0);
            acc[1][0] = __builtin_amdgcn_mfma_f32_16x16x32_bf16(a[1][p], buf0[p], acc[1][0], 0, 0, 0);
        }
        load_group_p(wp + 8192, lane, buf0);
        #pragma unroll
        for (int p = 0; p < 8; ++p) {
            acc[0][1] = __builtin_amdgcn_mfma_f32_16x16x32_bf16(a[0][p], buf1[p], acc[0][1], 0, 0, 0);
            acc[1][1] = __builtin_amdgcn_mfma_f32_16x16x32_bf16(a[1][p], buf1[p], acc[1][1], 0, 0, 0);
        }
        store_H(H, j, quad, l16, acc, bt0, bt1);
        wp += 8192;
    }
    __syncthreads();

    // ---- layer 3 A-frags from LDS ----
    #pragma unroll
    for (int i = 0; i < 2; ++i)
        #pragma unroll
        for (int s = 0; s < 8; ++s) {
            int row = i * 16 + l16;
            a[i][s] = *(const bf16x8*)(H + row * 256 + (((s * 4 + quad) + row) & 31) * 8);
        }

    // ---- epilogue metadata (once): tile graph range + per-row graph ids ----
    const bool fulltile = (r0g + 31 < N_NODES);
    int gfirst = (r0g < N_NODES) ? batch[r0g] : -1;
    int glastE = -2;
    if (r0g < N_NODES) {
        int mlast = r0g + 31;
        if (mlast >= N_NODES) mlast = N_NODES - 1;
        glastE = batch[mlast];
    }
    int gm[2][4];
    #pragma unroll
    for (int i = 0; i < 2; ++i)
        #pragma unroll
        for (int rr = 0; rr < 4; ++rr) {
            int m = r0g + i * 16 + quad * 4 + rr;
            gm[i][rr] = (m < N_NODES) ? batch[m] : -1;
        }
    const bool fast = fulltile && (gfirst == glastE);

    // ---- layer 3: groups 24..31 (4 slabs), pooled atomic output ----
    #pragma unroll 1
    for (int j = 0; j < 4; ++j) {
        load_group_p(wp + 4096, lane, buf1);
        float bt0 = bo[j * 32 + l16];
        float bt1 = bo[j * 32 + 16 + l16];
        f32x4 acc[2][2] = {};
        #pragma unroll
        for (int p = 0; p < 8; ++p) {
            acc[0][0] = __builtin_amdgcn_mfma_f32_16x16x32_bf16(a[0][p], buf0[p], acc[0][0], 0, 0, 0);
            acc[1][0] = __builtin_amdgcn_mfma_f32_16x16x32_bf16(a[1][p], buf0[p], acc[1][0], 0, 0, 0);
        }
        load_group_p(wp + 8192, lane, buf0);  // last iter reads past Wp into pairBuf (harmless)
        #pragma unroll
        for (int p = 0; p < 8; ++p) {
            acc[0][1] = __builtin_amdgcn_mfma_f32_16x16x32_bf16(a[0][p], buf1[p], acc[0][1], 0, 0, 0);
            acc[1][1] = __builtin_amdgcn_mfma_f32_16x16x32_bf16(a[1][p], buf1[p], acc[1][1], 0, 0, 0);
        }

        if (fast) {
            #pragma unroll
            for (int t = 0; t < 2; ++t) {
                float sum = 0.f;
                #pragma unroll
                for (int i = 0; i < 2; ++i)
                    #pragma unroll
                    for (int rr = 0; rr < 4; ++rr) sum += acc[i][t][rr];
                sum += __shfl_xor(sum, 16, 64);
                sum += __shfl_xor(sum, 32, 64);
                if (quad == 0) {
                    int c = j * 32 + t * 16 + l16;
                    float bb = t ? bt1 : bt0;
                    atomicAdd(out + (size_t)gfirst * OUT_DIM + c, sum + 32.f * bb);
                }
            }
        } else {
            // per-graph masked reduction: one atomic per col per graph
            #pragma unroll 1
            for (int dg = gfirst; dg <= glastE; ++dg) {
                float cntv = 0.f;
                #pragma unroll
                for (int i = 0; i < 2; ++i)
                    #pragma unroll
                    for (int rr = 0; rr < 4; ++rr)
                        if (gm[i][rr] == dg) cntv += 1.f;
                cntv += __shfl_xor(cntv, 16, 64);
                cntv += __shfl_xor(cntv, 32, 64);
                #pragma unroll
                for (int t = 0; t < 2; ++t) {
                    float s = 0.f;
                    #pragma unroll
                    for (int i = 0; i < 2; ++i)
                        #pragma unroll
                        for (int rr = 0; rr < 4; ++rr)
                            if (gm[i][rr] == dg) s += acc[i][t][rr];
                    s += __shfl_xor(s, 16, 64);
                    s += __shfl_xor(s, 32, 64);
                    if (quad == 0) {
                        int c = j * 32 + t * 16 + l16;
                        float bb = t ? bt1 : bt0;
                        atomicAdd(out + (size_t)dg * OUT_DIM + c, s + cntv * bb);
                    }
                }
            }
        }
        wp += 8192;
    }
}

extern "C" void kernel_launch(void* const* d_in, const int* in_sizes, int n_in,
                              void* d_out, int out_size, void* d_ws, size_t ws_size,
                              hipStream_t stream) {
    const float* x  = (const float*)d_in[0];
    const int*   ei = (const int*)d_in[1];
    const int*   bi = (const int*)d_in[2];
    const float* W1 = (const float*)d_in[3];
    const float* b1 = (const float*)d_in[4];
    const float* W2 = (const float*)d_in[5];
    const float* b2 = (const float*)d_in[6];
    const float* Wo = (const float*)d_in[7];
    const float* bo = (const float*)d_in[8];
    float* out = (float*)d_out;

    __bf16* A  = (__bf16*)d_ws;                        // [M_PAD][128]
    __bf16* xb = A + (size_t)M_PAD * IN_DIM;           // [N_NODES][128]
    __bf16* Wp = xb + (size_t)N_NODES * IN_DIM;        // [131072] packed frag-ordered
    unsigned* pairBuf = (unsigned*)(Wp + WP_TOTAL);    // [NB*BCAP]
    int* gcursor  = (int*)(pairBuf + (size_t)NB * BCAP);   // [NB*GC_STRIDE] padded

    // ---- zero the padded per-bucket cursors ----
    hipMemsetAsync(gcursor, 0, NB * GC_STRIDE * sizeof(int), stream);

    // ---- fused init + edge binning (bucket blocks first, 4-item init blocks) ----
    init_bucket_kernel<<<GRID_IB, 256, 0, stream>>>(
        x, W1, W2, Wo, ei, xb, A + (size_t)N_NODES * IN_DIM, Wp, out, gcursor, pairBuf);

    // ---- fused CSR-in-LDS + gather aggregate ----
    aggB_kernel<<<NB, AGG_THREADS, 0, stream>>>(pairBuf, gcursor, xb, A);

    // ---- fused MLP + pool (v2 core frozen; low-atomic epilogue) ----
    mlp_fused<<<M_PAD / 32, 64, 0, stream>>>(A, Wp, b1, b2, bo, out, bi);
}